// Round 3
// baseline (149.779 us; speedup 1.0000x reference)
//
#include <hip/hip_runtime.h>
#include <stdint.h>

// B=8, N=1024, I=256, O=256, R=8
// out[b,dst,o] = (sum_{src,r} adj[b,src,dst,r] * f[b,src,r,o]) / clip(sum adj, 1e-16)
//
//  prep   : x fp32->bf16 [8192][256]; weight[r][i][o] -> W_t[o*8+r][i] bf16 (merged kernel)
//  k1     : f_t[b][o][k=src*8+r] = x @ W   (bf16 MFMA, 128x128 tiles)
//  k2     : pout = adj^T @ f_t. MT=64 dst x NT=256 o, 512 thr (8 waves 2x4), KSPLIT=2,
//           KT=64 (8 src), 2-phase double-buffered LDS (issue-early staging), fused
//           fp32 denom. b=bid&7 pins batch to XCD (f_t[b]=4MB = one L2).
//  k3     : sum split-K partials, divide by clamped denom.

typedef float          floatx4  __attribute__((ext_vector_type(4)));
typedef short          shortx8  __attribute__((ext_vector_type(8)));
typedef unsigned short ushortx4 __attribute__((ext_vector_type(4)));
typedef unsigned short ushortx8 __attribute__((ext_vector_type(8)));

__device__ __forceinline__ unsigned short f2bf(float f) {
  union { float f; unsigned int u; } v; v.f = f;
  unsigned int u = v.u + 0x7FFFu + ((v.u >> 16) & 1u);  // RNE
  return (unsigned short)(u >> 16);
}

__device__ __forceinline__ void gload16(const void* g, void* l) {
  __builtin_amdgcn_global_load_lds((__attribute__((address_space(1))) void*)g,
                                   (__attribute__((address_space(3))) void*)l,
                                   16, 0, 0);
}

// ---------------- merged prep ----------------
__global__ __launch_bounds__(256) void prep_xw(const float* __restrict__ x,
                                               const float* __restrict__ w,
                                               unsigned short* __restrict__ xbf,
                                               unsigned short* __restrict__ wt) {
  int bid = blockIdx.x;
  if (bid < 1024) {                                // x: 262144 threads x 8 elems
    int t = bid * 256 + threadIdx.x;
    const float4* p = (const float4*)x + (size_t)t * 2;
    float4 a = p[0], b4 = p[1];
    ushortx8 o;
    o[0] = f2bf(a.x);  o[1] = f2bf(a.y);  o[2] = f2bf(a.z);  o[3] = f2bf(a.w);
    o[4] = f2bf(b4.x); o[5] = f2bf(b4.y); o[6] = f2bf(b4.z); o[7] = f2bf(b4.w);
    *(ushortx8*)(xbf + (size_t)t * 8) = o;
  } else {                                         // w: 524288 scalar
    int id = (bid - 1024) * 256 + threadIdx.x;
    int r = id >> 16, i = (id >> 8) & 255, o = id & 255;
    float v = w[((size_t)(r * 256 + i) << 8) + o];
    wt[((size_t)(o * 8 + r) << 8) + i] = f2bf(v);
  }
}

// ---------------- kernel 1: f_t = x @ W ----------------
__global__ __launch_bounds__(256) void k1_gemm(const unsigned short* __restrict__ xbf,
                                               const unsigned short* __restrict__ wt,
                                               unsigned short* __restrict__ ft) {
  int bid = blockIdx.x;                            // 64 m-tiles x 16 n-tiles
  int m0 = (bid >> 4) * 128, n0 = (bid & 15) * 128;
  int l = threadIdx.x & 63, w = threadIdx.x >> 6;
  int lr = l & 15, lg = l >> 4;
  int mw = m0 + (w >> 1) * 64, nw = n0 + (w & 1) * 64;

  floatx4 acc[4][4] = {};
#pragma unroll
  for (int ks = 0; ks < 8; ++ks) {                 // K = 256 = 8 * 32
    shortx8 a[4], b[4];
#pragma unroll
    for (int mi = 0; mi < 4; ++mi)
      a[mi] = *(const shortx8*)(xbf + (size_t)(mw + mi * 16 + lr) * 256 + ks * 32 + lg * 8);
#pragma unroll
    for (int ni = 0; ni < 4; ++ni)
      b[ni] = *(const shortx8*)(wt + (size_t)(nw + ni * 16 + lr) * 256 + ks * 32 + lg * 8);
#pragma unroll
    for (int mi = 0; mi < 4; ++mi)
#pragma unroll
      for (int ni = 0; ni < 4; ++ni)
        acc[mi][ni] = __builtin_amdgcn_mfma_f32_16x16x32_bf16(a[mi], b[ni], acc[mi][ni], 0, 0, 0);
  }
#pragma unroll
  for (int mi = 0; mi < 4; ++mi) {
#pragma unroll
    for (int ni = 0; ni < 4; ++ni) {
      int np = nw + ni * 16 + lr;
      int o = np >> 3, r = np & 7;
#pragma unroll
      for (int reg = 0; reg < 4; ++reg) {
        int row = mw + mi * 16 + lg * 4 + reg;     // global (b,src)
        int b8 = row >> 10, src = row & 1023;
        ft[((size_t)(b8 * 256 + o) << 13) + src * 8 + r] = f2bf(acc[mi][ni][reg]);
      }
    }
  }
}

// ---------------- kernel 2: pout = adj^T @ f_t (+ denom) ----------------
// 256 blocks x 512 thr. Block: batch b, 64 dst, 256 o, K-half (4096 k = 64 kt x 8 src).
#define BHALF 16384   // Blds half: 256 o x 64 k shorts
#define AHALF 4096    // Alds half:  64 dst x 64 k shorts
__global__ __launch_bounds__(512) void k2_gemm(const float* __restrict__ adj,
                                               const unsigned short* __restrict__ ft,
                                               float* __restrict__ pout,
                                               float* __restrict__ dpart) {
  __shared__ __align__(16) unsigned short Blds[2 * BHALF];  // 64KB
  __shared__ __align__(16) unsigned short Alds[2 * AHALF];  // 16KB
  __shared__ float dsums[512];
  __shared__ float denr[64];

  int bid = blockIdx.x;
  int kc = bid >> 7;                  // 0,1
  int inner = bid & 127;
  int b = inner & 7;                  // XCD pin: all blocks of batch b on XCD b
  int dst0 = (inner >> 3) * 64;       // 16 dst-tiles

  int t = threadIdx.x, l = t & 63, w = t >> 6;    // 8 waves
  int lr = l & 15, lg = l >> 4;
  int wm = w >> 2, wo = w & 3;                    // wave -> (m-half, o-quarter)

  // A-staging: thread t -> dst_l, r-half, src base (2 float4 per kt)
  int dst_l = (t >> 1) & 63;
  int rh = (t & 1) * 4;
  int sA = t >> 7;                    // 0..3 (+4 for j=1)

  // B-staging: per wave, 4 issues of 8 o-rows; pre-swizzled source chunk
  int csw = (l & 7) ^ (l >> 3);

  const size_t adj_b = (size_t)b << 23;
  const unsigned short* ftb = ft + ((size_t)b << 21);
  int src_base = kc * 512;
  const int KT = 64;

  float dsum = 0.f;
  floatx4 acc[2][4] = {};
  float4 av[2];

  // ---- helpers ----
  auto A_load = [&](int kt, float4* v) {
#pragma unroll
    for (int j = 0; j < 2; ++j) {
      int src_l = sA + j * 4;
      v[j] = *(const float4*)(adj + adj_b + ((size_t)(src_base + kt * 8 + src_l) << 13)
                              + ((size_t)(dst0 + dst_l) << 3) + rh);
    }
  };
  auto A_store = [&](int half, const float4* v) {
#pragma unroll
    for (int j = 0; j < 2; ++j) {
      int src_l = sA + j * 4;
      float4 q = v[j];
      dsum += q.x + q.y + q.z + q.w;
      ushortx4 h;
      h[0] = f2bf(q.x); h[1] = f2bf(q.y); h[2] = f2bf(q.z); h[3] = f2bf(q.w);
      int slot = src_l ^ (dst_l & 7);
      *(ushortx4*)&Alds[half * AHALF + dst_l * 64 + slot * 8 + rh] = h;
    }
  };
  auto B_stage = [&](int kt, int half) {
    int kbase = (src_base + kt * 8) * 8;
#pragma unroll
    for (int i = 0; i < 4; ++i) {
      int orow = i * 64 + w * 8 + (l >> 3);
      const unsigned short* g = ftb + ((size_t)orow << 13) + kbase + (csw << 3);
      gload16(g, &Blds[half * BHALF + (i * 64 + w * 8) * 64]);  // wave-uniform base
    }
  };
  auto compute = [&](int half) {
#pragma unroll
    for (int s = 0; s < 2; ++s) {
      int slotbase = s * 4 + lg;
      shortx8 af[2], bfr[4];
#pragma unroll
      for (int mi = 0; mi < 2; ++mi) {
        int row = wm * 32 + mi * 16 + lr;
        af[mi] = *(const shortx8*)&Alds[half * AHALF + row * 64 + ((slotbase ^ (row & 7)) << 3)];
      }
#pragma unroll
      for (int ni = 0; ni < 4; ++ni) {
        int oc = wo * 64 + ni * 16 + lr;
        bfr[ni] = *(const shortx8*)&Blds[half * BHALF + oc * 64 + ((slotbase ^ (oc & 7)) << 3)];
      }
#pragma unroll
      for (int mi = 0; mi < 2; ++mi)
#pragma unroll
        for (int ni = 0; ni < 4; ++ni)
          acc[mi][ni] = __builtin_amdgcn_mfma_f32_16x16x32_bf16(af[mi], bfr[ni], acc[mi][ni], 0, 0, 0);
    }
  };

  // ---- prologue: stage kt=0 into half 0 ----
  A_load(0, av);
  B_stage(0, 0);
  A_store(0, av);
  __syncthreads();

  // ---- 2-phase pipelined K loop ----
  for (int kt = 0; kt < KT; ++kt) {
    int cur = kt & 1, nxt = cur ^ 1;
    bool has = (kt + 1) < KT;
    if (has) A_load(kt + 1, av);      // issue A loads first (vmcnt-counted ahead of B)
    if (has) B_stage(kt + 1, nxt);    // async global->LDS, in flight during compute
    compute(cur);
    if (has) A_store(nxt, av);        // convert + ds_write after compute
    __syncthreads();                  // drains vmcnt (B) + lgkm (A writes)
  }

  // ---- deterministic denom reduction: 8 threads per dst row ----
  dsums[t] = dsum;
  __syncthreads();
  if (t < 64) {
    float s = 0.f;
#pragma unroll
    for (int sh = 0; sh < 4; ++sh) {
      s += dsums[sh * 128 + t * 2];
      s += dsums[sh * 128 + t * 2 + 1];
    }
    denr[t] = s;
  }
  __syncthreads();

  // ---- write partials ----
#pragma unroll
  for (int mi = 0; mi < 2; ++mi) {
#pragma unroll
    for (int reg = 0; reg < 4; ++reg) {
      int row = dst0 + wm * 32 + mi * 16 + lg * 4 + reg;
#pragma unroll
      for (int ni = 0; ni < 4; ++ni) {
        int col = wo * 64 + ni * 16 + lr;
        pout[(size_t)kc * 2097152 + (((size_t)b << 10) + row) * 256 + col] = acc[mi][ni][reg];
      }
    }
  }
  if (t < 64) dpart[kc * 8192 + (b << 10) + dst0 + t] = denr[t];
}

// ---------------- kernel 3: split-K reduce + normalize ----------------
__global__ __launch_bounds__(256) void k3_reduce(const float* __restrict__ pout,
                                                 const float* __restrict__ dpart,
                                                 float* __restrict__ outp) {
  int bid = blockIdx.x;              // b*1024 + dst
  size_t base = (size_t)bid * 256 + threadIdx.x;
  float v = pout[base] + pout[2097152 + base];
  float d = dpart[bid] + dpart[8192 + bid];
  outp[base] = v / fmaxf(d, 1e-16f);
}

// ---------------- launch ----------------
extern "C" void kernel_launch(void* const* d_in, const int* in_sizes, int n_in,
                              void* d_out, int out_size, void* d_ws, size_t ws_size,
                              hipStream_t stream) {
  const float* x   = (const float*)d_in[0];
  const float* adj = (const float*)d_in[1];
  const float* w   = (const float*)d_in[2];
  float* out = (float*)d_out;

  char* ws = (char*)d_ws;
  unsigned short* ft  = (unsigned short*)(ws);              // 32 MB
  unsigned short* xbf = (unsigned short*)(ws + 33554432);   //  4 MB
  unsigned short* wt  = (unsigned short*)(ws + 37748736);   //  1 MB
  float* pout  = (float*)(ws + 38797312);                   // 16 MB
  float* dpart = (float*)(ws + 55574528);                   // 64 KB

  prep_xw<<<3072, 256, 0, stream>>>(x, w, xbf, wt);
  k1_gemm<<<1024, 256, 0, stream>>>(xbf, wt, ft);
  k2_gemm<<<256, 512, 0, stream>>>(adj, ft, pout, dpart);
  k3_reduce<<<8192, 256, 0, stream>>>(pout, dpart, out);
}